// Round 10
// baseline (250.886 us; speedup 1.0000x reference)
//
#include <hip/hip_runtime.h>
#include <math.h>

#define ROWS 8192
#define NCOL 2048
#define V 32
#define WPB 4                 // waves (rows) per block
#define THREADS (WPB * 64)

// DPP ctrl encodings (gfx9/CDNA). NOTE direction convention (per GPUOpen
// cross-lane ops + rocPRIM dpp scan): row_shr:N -> dst[i] = src[i-N];
// row_shl:N -> dst[i] = src[i+N]. (Round 9 had these swapped -> wrong sort.)
#define DPP_XOR1  0xB1        // quad_perm [1,0,3,2]
#define DPP_XOR2  0x4E        // quad_perm [2,3,0,1]
#define DPP_XOR3  0x1B        // quad_perm [3,2,1,0]
#define DPP_XOR7  0x141       // row_half_mirror (xor 7 within 8)
#define DPP_XOR15 0x140       // row_mirror (xor 15 within 16)
#define DPP_XOR8  0x128       // row_ror:8 == xor 8 within 16 (symmetric)
#define DPP_SHL4  0x104       // row_shl:4  dst i = src i+4 (valid i%16 <= 11)
#define DPP_SHR4  0x114       // row_shr:4  dst i = src i-4 (valid i%16 >= 4)

// static compare-exchange: ascending, both indices compile-time
__device__ __forceinline__ void ce(float& a, float& b) {
  const float lo = fminf(a, b);
  const float hi = fmaxf(a, b);
  a = lo; b = hi;
}

// med3(a,b,-inf)=min; med3(a,b,+inf)=max. One VALU op per directed CE.
__device__ __forceinline__ float ce_dir(float a, float b, float cdir) {
  return __builtin_amdgcn_fmed3f(a, b, cdir);
}

__device__ __forceinline__ float dirc(int lane, int bit) {
  return (lane & bit) ? INFINITY : -INFINITY;
}

// lane-xor exchange on the VALU pipe (v_mov_b32_dpp), NOT the DS pipe
template <int CTRL>
__device__ __forceinline__ float dpp_x(float x) {
  return __int_as_float(__builtin_amdgcn_update_dpp(
      0, __float_as_int(x), CTRL, 0xF, 0xF, true));
}

// lane exchange on DS pipe; addr = (lane^mask)<<2, hoisted per pass
__device__ __forceinline__ float bperm(int addr, float x) {
  return __int_as_float(__builtin_amdgcn_ds_bpermute(addr, __float_as_int(x)));
}

// xor pass (same reg index v), DPP variant: 2 VALU/elem
template <int CTRL>
__device__ __forceinline__ void dpp_xor_pass(float r[V], float cdir) {
#pragma unroll
  for (int v = 0; v < V; ++v) r[v] = ce_dir(r[v], dpp_x<CTRL>(r[v]), cdir);
}

// xor4 pass: partner lane^4 within the 16-lane row.
// (lane&4)==0 needs src i+4 -> row_shl:4; (lane&4)!=0 needs src i-4 ->
// row_shr:4. Invalid lanes of each shift read 0 but are never selected.
__device__ __forceinline__ void dpp_xor4_pass(float r[V], float cdir, int lane) {
  const bool hi = (lane & 4) != 0;
#pragma unroll
  for (int v = 0; v < V; ++v) {
    const float a = dpp_x<DPP_SHL4>(r[v]);  // src i+4 (for lower lanes)
    const float b = dpp_x<DPP_SHR4>(r[v]);  // src i-4 (for upper lanes)
    r[v] = ce_dir(r[v], hi ? b : a, cdir);
  }
}

// flip pass (reg partner v^31), DPP variant; 4-reg self-contained units
template <int CTRL>
__device__ __forceinline__ void dpp_flip_pass(float r[V], float cdir) {
#pragma unroll
  for (int q = 0; q < 8; ++q) {
    const int vA = 2 * q, vB = 2 * q + 1;
    float o[4];
    o[0] = dpp_x<CTRL>(r[vA ^ 31]);
    o[1] = dpp_x<CTRL>(r[vB ^ 31]);
    o[2] = dpp_x<CTRL>(r[vB]);
    o[3] = dpp_x<CTRL>(r[vA]);
    r[vA]      = ce_dir(r[vA],      o[0], cdir);
    r[vB]      = ce_dir(r[vB],      o[1], cdir);
    r[vB ^ 31] = ce_dir(r[vB ^ 31], o[2], cdir);
    r[vA ^ 31] = ce_dir(r[vA ^ 31], o[3], cdir);
  }
}

// xor pass, DS variant
__device__ __forceinline__ void ds_xor_pass(float r[V], int addr, float cdir) {
#pragma unroll
  for (int c = 0; c < V; c += 8) {
    float o[8];
#pragma unroll
    for (int u = 0; u < 8; ++u) o[u] = bperm(addr, r[c + u]);
#pragma unroll
    for (int u = 0; u < 8; ++u) r[c + u] = ce_dir(r[c + u], o[u], cdir);
  }
}

// flip pass, DS variant; 4-reg units
__device__ __forceinline__ void ds_flip_pass(float r[V], int addr, float cdir) {
#pragma unroll
  for (int q = 0; q < 8; ++q) {
    const int vA = 2 * q, vB = 2 * q + 1;
    float o[4];
    o[0] = bperm(addr, r[vA ^ 31]);
    o[1] = bperm(addr, r[vB ^ 31]);
    o[2] = bperm(addr, r[vB]);
    o[3] = bperm(addr, r[vA]);
    r[vA]      = ce_dir(r[vA],      o[0], cdir);
    r[vB]      = ce_dir(r[vB],      o[1], cdir);
    r[vB ^ 31] = ce_dir(r[vB ^ 31], o[2], cdir);
    r[vA ^ 31] = ce_dir(r[vA ^ 31], o[3], cdir);
  }
}

// full sort of one 2048-row held as r[32] per lane (e = lane*32 + v).
// Only ~40 live VGPRs -> no spill, high occupancy (the 64-reg both-arrays
// version forced spill@(256,4) / 2 blocks@(256,3) in rounds 7/8).
__device__ __forceinline__ void sort_row(float r[V], const int lane) {
  // ---- Phase 1: stages k = 2..32, in-lane, fully static ----
#pragma unroll
  for (int k = 2; k <= V; k <<= 1) {
#pragma unroll
    for (int v = 0; v < V; ++v)
      if ((v & (k >> 1)) == 0) ce(r[v], r[v ^ (k - 1)]);
#pragma unroll
    for (int j = k >> 2; j >= 1; j >>= 1)
#pragma unroll
      for (int v = 0; v < V; ++v)
        if ((v & j) == 0) ce(r[v], r[v | j]);
  }
  // ---- Phase 2: merge stages kb = 1..32 (compact loops: I-cache) ----
  // DPP masks {1,2,3,7,15,8, 4-trick}; DS only {16,31,63}: 96 bperm/array.
#pragma unroll 1
  for (int kb = 1; kb <= 32; kb <<= 1) {
    const float cf = dirc(lane, kb);
    if (kb == 1)      dpp_flip_pass<DPP_XOR1>(r, cf);
    else if (kb == 2) dpp_flip_pass<DPP_XOR3>(r, cf);
    else if (kb == 4) dpp_flip_pass<DPP_XOR7>(r, cf);
    else if (kb == 8) dpp_flip_pass<DPP_XOR15>(r, cf);
    else ds_flip_pass(r, (lane ^ (2 * kb - 1)) << 2, cf);
#pragma unroll 1
    for (int m = kb >> 1; m >= 1; m >>= 1) {
      const float c = dirc(lane, m);
      if (m == 1)      dpp_xor_pass<DPP_XOR1>(r, c);
      else if (m == 2) dpp_xor_pass<DPP_XOR2>(r, c);
      else if (m == 4) dpp_xor4_pass(r, c, lane);
      else if (m == 8) dpp_xor_pass<DPP_XOR8>(r, c);
      else ds_xor_pass(r, (lane ^ m) << 2, c);
    }
    // in-lane tail j = 16..1
#pragma unroll
    for (int j = 16; j >= 1; j >>= 1)
#pragma unroll
      for (int v = 0; v < V; ++v)
        if ((v & j) == 0) ce(r[v], r[v | j]);
  }
}

__global__ __launch_bounds__(THREADS, 4) void sort_mse_kernel(
    const float* __restrict__ pred, const float* __restrict__ targ,
    float* __restrict__ out) {
  // per-wave 8 KB stash; chunk swizzle q^(lane&7) -> b128 conflict-free
  __shared__ float4 stash[WPB * 512];
  const int lane = threadIdx.x & 63;
  const int wave = threadIdx.x >> 6;
  const int row = blockIdx.x * WPB + wave;
  const size_t base = (size_t)row * NCOL + (size_t)lane * V;
  float4* ws = &stash[wave * 512 + lane * 8];

  float r[V];
  const float4* p4 = (const float4*)(pred + base);
#pragma unroll
  for (int q = 0; q < 8; ++q) {
    const float4 a = p4[q];
    r[4 * q + 0] = a.x; r[4 * q + 1] = a.y;
    r[4 * q + 2] = a.z; r[4 * q + 3] = a.w;
  }
  sort_row(r, lane);
#pragma unroll
  for (int q = 0; q < 8; ++q)
    ws[q ^ (lane & 7)] =
        make_float4(r[4 * q + 0], r[4 * q + 1], r[4 * q + 2], r[4 * q + 3]);

  const float4* t4 = (const float4*)(targ + base);
#pragma unroll
  for (int q = 0; q < 8; ++q) {
    const float4 a = t4[q];
    r[4 * q + 0] = a.x; r[4 * q + 1] = a.y;
    r[4 * q + 2] = a.z; r[4 * q + 3] = a.w;
  }
  sort_row(r, lane);

  // ranks match at identical (lane, v): diff vs stashed sorted-p
  float acc = 0.f;
#pragma unroll
  for (int q = 0; q < 8; ++q) {
    const float4 s = ws[q ^ (lane & 7)];
    float d;
    d = s.x - r[4 * q + 0]; acc = fmaf(d, d, acc);
    d = s.y - r[4 * q + 1]; acc = fmaf(d, d, acc);
    d = s.z - r[4 * q + 2]; acc = fmaf(d, d, acc);
    d = s.w - r[4 * q + 3]; acc = fmaf(d, d, acc);
  }
#pragma unroll
  for (int off = 32; off > 0; off >>= 1) acc += __shfl_down(acc, off, 64);
  if (lane == 0) {
    unsafeAtomicAdd(out, acc * (1.0f / ((float)ROWS * (float)NCOL)));
  }
}

extern "C" void kernel_launch(void* const* d_in, const int* in_sizes, int n_in,
                              void* d_out, int out_size, void* d_ws, size_t ws_size,
                              hipStream_t stream) {
  const float* pred = (const float*)d_in[0];
  const float* targ = (const float*)d_in[1];
  float* out = (float*)d_out;

  hipMemsetAsync(out, 0, sizeof(float), stream);  // d_out is re-poisoned 0xAA
  sort_mse_kernel<<<ROWS / WPB, THREADS, 0, stream>>>(pred, targ, out);
}